// Round 4
// baseline (307.878 us; speedup 1.0000x reference)
//
#include <hip/hip_runtime.h>

#define B_TOTAL 2000000
#define CPB 1024  // columns per block (256 threads x 4 adjacent cols/thread)

// POLLU RHS: 25 fluxes, 20 species.
// conc: [20, B] species-major; out: [B, 20].
// v5: ZERO LDS, ZERO barriers. Each thread owns 4 adjacent columns:
//     - loads: 20x global_load_dwordx4 (wave reads 1KB contiguous/instr)
//     - compute: dy overwrites c4 in place, per float4 component
//     - stores: thread's 80 outputs are a dense 16B-aligned 320B span of out
//       -> 20x global_store_dwordx4 with register (compile-time) shuffles.
//     No inter-wave sync anywhere; L2 merges the wave's 20KB store window.
__global__ __launch_bounds__(256) void pollu_kernel(
    const float* __restrict__ conc,
    const float* __restrict__ k,
    float* __restrict__ out)
{
    const int t = threadIdx.x;
    const int base = blockIdx.x * CPB;
    const int ncols = min(CPB, B_TOTAL - base);

    // k: uniform + constant-indexed -> SGPR loads, no LDS, no barrier.
    const float k0 = k[0],  k1 = k[1],  k2 = k[2],  k3 = k[3],  k4 = k[4];
    const float k5 = k[5],  k6 = k[6],  k7 = k[7],  k8 = k[8],  k9 = k[9];
    const float k10 = k[10], k11 = k[11], k12 = k[12], k13 = k[13], k14 = k[14];
    const float k15 = k[15], k16 = k[16], k17 = k[17], k18 = k[18], k19 = k[19];
    const float k20 = k[20], k21 = k[21], k22 = k[22], k23 = k[23], k24 = k[24];

// Compute 25 fluxes from C(s), then overwrite C(s) with dy[s].
// Safe in-place: every C read happens in the flux block, before any C write.
#define POLLU_FLUX_DY(C)                                                      \
        const float f1  = k0  * C(0);                                         \
        const float f2  = k1  * C(1)  * C(3);                                 \
        const float f3  = k2  * C(4)  * C(1);                                 \
        const float f4  = k3  * C(6);                                         \
        const float f5  = k4  * C(6);                                         \
        const float f6  = k5  * C(6)  * C(5);                                 \
        const float f7  = k6  * C(8);                                         \
        const float f8  = k7  * C(8)  * C(5);                                 \
        const float f9  = k8  * C(10) * C(1);                                 \
        const float f10 = k9  * C(10) * C(0);                                 \
        const float f11 = k10 * C(12);                                        \
        const float f12 = k11 * C(9)  * C(1);                                 \
        const float f13 = k12 * C(13);                                        \
        const float f14 = k13 * C(0)  * C(5);                                 \
        const float f15 = k14 * C(2);                                         \
        const float f16 = k15 * C(3);                                         \
        const float f17 = k16 * C(3);                                         \
        const float f18 = k17 * C(15);                                        \
        const float f19 = k18 * C(15);                                        \
        const float f20 = k19 * C(16) * C(5);                                 \
        const float f21 = k20 * C(18);                                        \
        const float f22 = k21 * C(18);                                        \
        const float f23 = k22 * C(0)  * C(3);                                 \
        const float f24 = k23 * C(18) * C(0);                                 \
        const float f25 = k24 * C(19);                                        \
        C(0)  = -f1 - f10 - f14 - f23 - f24 + f2 + f3 + f9 + f11 + f12 + f22 + f25; \
        C(1)  = -f2 - f3 - f9 - f12 + f1 + f21;                               \
        C(2)  = -f15 + f1 + f17 + f19 + f22;                                  \
        C(3)  = -f2 - f16 - f17 - f23 + f15;                                  \
        C(4)  = -f3 + 2.0f * f4 + f6 + f7 + f13 + f20;                        \
        C(5)  = -f6 - f8 - f14 - f20 + f3 + 2.0f * f18;                       \
        C(6)  = -f4 - f5 - f6 + f13;                                          \
        C(7)  =  f4 + f5 + f6 + f7;                                           \
        C(8)  = -f7 - f8;                                                     \
        C(9)  = -f12 + f7 + f9;                                               \
        C(10) = -f9 - f10 + f8 + f11;                                         \
        C(11) =  f9;                                                          \
        C(12) = -f11 + f10;                                                   \
        C(13) = -f13 + f12;                                                   \
        C(14) =  f14;                                                         \
        C(15) = -f18 - f19 + f16;                                             \
        C(16) = -f20;                                                         \
        C(17) =  f20;                                                         \
        C(18) = -f21 - f22 - f24 + f23 + f25;                                 \
        C(19) = -f25 + f24;

#define CX(s) c4[s].x
#define CY(s) c4[s].y
#define CZ(s) c4[s].z
#define CW(s) c4[s].w
#define CA(s) c[s]

    if (ncols == CPB) {
        // ---- load: 20 x global_load_dwordx4, 1KB contiguous per wave-instr ----
        float4 c4[20];
        const size_t off = (size_t)base + (size_t)(4 * t);
#pragma unroll
        for (int s = 0; s < 20; ++s)
            c4[s] = *(const float4*)(conc + (size_t)s * B_TOTAL + off);

        // ---- compute: dy overwrites c4 component-wise ----
        { POLLU_FLUX_DY(CX) }
        { POLLU_FLUX_DY(CY) }
        { POLLU_FLUX_DY(CZ) }
        { POLLU_FLUX_DY(CW) }

        // ---- store: thread's 4 columns = dense 320B span, 20 float4s ----
        // o[j*5+g] = species {4g..4g+3} of column j (component j of c4).
        float4* o = (float4*)(out + (size_t)(base + 4 * t) * 20);
        o[0]  = make_float4(c4[0].x,  c4[1].x,  c4[2].x,  c4[3].x);
        o[1]  = make_float4(c4[4].x,  c4[5].x,  c4[6].x,  c4[7].x);
        o[2]  = make_float4(c4[8].x,  c4[9].x,  c4[10].x, c4[11].x);
        o[3]  = make_float4(c4[12].x, c4[13].x, c4[14].x, c4[15].x);
        o[4]  = make_float4(c4[16].x, c4[17].x, c4[18].x, c4[19].x);
        o[5]  = make_float4(c4[0].y,  c4[1].y,  c4[2].y,  c4[3].y);
        o[6]  = make_float4(c4[4].y,  c4[5].y,  c4[6].y,  c4[7].y);
        o[7]  = make_float4(c4[8].y,  c4[9].y,  c4[10].y, c4[11].y);
        o[8]  = make_float4(c4[12].y, c4[13].y, c4[14].y, c4[15].y);
        o[9]  = make_float4(c4[16].y, c4[17].y, c4[18].y, c4[19].y);
        o[10] = make_float4(c4[0].z,  c4[1].z,  c4[2].z,  c4[3].z);
        o[11] = make_float4(c4[4].z,  c4[5].z,  c4[6].z,  c4[7].z);
        o[12] = make_float4(c4[8].z,  c4[9].z,  c4[10].z, c4[11].z);
        o[13] = make_float4(c4[12].z, c4[13].z, c4[14].z, c4[15].z);
        o[14] = make_float4(c4[16].z, c4[17].z, c4[18].z, c4[19].z);
        o[15] = make_float4(c4[0].w,  c4[1].w,  c4[2].w,  c4[3].w);
        o[16] = make_float4(c4[4].w,  c4[5].w,  c4[6].w,  c4[7].w);
        o[17] = make_float4(c4[8].w,  c4[9].w,  c4[10].w, c4[11].w);
        o[18] = make_float4(c4[12].w, c4[13].w, c4[14].w, c4[15].w);
        o[19] = make_float4(c4[16].w, c4[17].w, c4[18].w, c4[19].w);
    } else {
        // ---- tail block (128 columns once): scalar fallback ----
        for (int col = base + t; col < B_TOTAL; col += 256) {
            float c[20];
#pragma unroll
            for (int s = 0; s < 20; ++s) c[s] = conc[(size_t)s * B_TOTAL + (size_t)col];
            { POLLU_FLUX_DY(CA) }
#pragma unroll
            for (int s = 0; s < 20; ++s) out[(size_t)col * 20 + s] = c[s];
        }
    }
}

extern "C" void kernel_launch(void* const* d_in, const int* in_sizes, int n_in,
                              void* d_out, int out_size, void* d_ws, size_t ws_size,
                              hipStream_t stream) {
    // d_in[0] = t (unused), d_in[1] = conc_in [20, B], d_in[2] = k [25]
    const float* conc = (const float*)d_in[1];
    const float* k    = (const float*)d_in[2];
    float* out        = (float*)d_out;

    const int block = 256;
    const int grid  = (B_TOTAL + CPB - 1) / CPB;  // 1954
    pollu_kernel<<<grid, block, 0, stream>>>(conc, k, out);
}

// Round 5
// 274.177 us; speedup vs baseline: 1.1229x; 1.1229x over previous
//
#include <hip/hip_runtime.h>

#define B_TOTAL 2000000
#define PAD 21  // 21 coprime with 32 banks -> conflict-free LDS writes

// POLLU RHS: 25 fluxes, 20 species, stoichiometry hard-coded.
// conc: [20, B] species-major (coalesced dword reads, one thread per column b)
// out:  [B, 20] -> staged through LDS so global stores are dense float4 sweeps
// v6 = v1 (best measured, ~79us kernel) with scalar-k micro-tweak:
//      k is uniform + constant-indexed -> SGPR loads, removing the sk[] LDS
//      stage and the startup barrier so global loads issue at cycle 0.
__global__ __launch_bounds__(256) void pollu_kernel(
    const float* __restrict__ conc,
    const float* __restrict__ k,
    float* __restrict__ out)
{
    __shared__ float lds[256 * PAD];  // 21504 B -> 7 blocks/CU

    const int t = threadIdx.x;
    const int blockStart = blockIdx.x * 256;
    const int b = blockStart + t;
    const int nvalid = min(256, B_TOTAL - blockStart);

    const float k0 = k[0],  k1 = k[1],  k2 = k[2],  k3 = k[3],  k4 = k[4];
    const float k5 = k[5],  k6 = k[6],  k7 = k[7],  k8 = k[8],  k9 = k[9];
    const float k10 = k[10], k11 = k[11], k12 = k[12], k13 = k[13], k14 = k[14];
    const float k15 = k[15], k16 = k[16], k17 = k[17], k18 = k[18], k19 = k[19];
    const float k20 = k[20], k21 = k[21], k22 = k[22], k23 = k[23], k24 = k[24];

    if (b < B_TOTAL) {
        const size_t B = (size_t)B_TOTAL;
        float c[20];
#pragma unroll
        for (int s = 0; s < 20; ++s) c[s] = conc[(size_t)s * B + (size_t)b];

        // flux r = k[r] * C[a_r] * C[b_r]  (index 20 == constant 1.0 row)
        const float f1  = k0  * c[0];
        const float f2  = k1  * c[1]  * c[3];
        const float f3  = k2  * c[4]  * c[1];
        const float f4  = k3  * c[6];
        const float f5  = k4  * c[6];
        const float f6  = k5  * c[6]  * c[5];
        const float f7  = k6  * c[8];
        const float f8  = k7  * c[8]  * c[5];
        const float f9  = k8  * c[10] * c[1];
        const float f10 = k9  * c[10] * c[0];
        const float f11 = k10 * c[12];
        const float f12 = k11 * c[9]  * c[1];
        const float f13 = k12 * c[13];
        const float f14 = k13 * c[0]  * c[5];
        const float f15 = k14 * c[2];
        const float f16 = k15 * c[3];
        const float f17 = k16 * c[3];
        const float f18 = k17 * c[15];
        const float f19 = k18 * c[15];
        const float f20 = k19 * c[16] * c[5];
        const float f21 = k20 * c[18];
        const float f22 = k21 * c[18];
        const float f23 = k22 * c[0]  * c[3];
        const float f24 = k23 * c[18] * c[0];
        const float f25 = k24 * c[19];

        float dy[20];
        dy[0]  = -f1 - f10 - f14 - f23 - f24 + f2 + f3 + f9 + f11 + f12 + f22 + f25;
        dy[1]  = -f2 - f3 - f9 - f12 + f1 + f21;
        dy[2]  = -f15 + f1 + f17 + f19 + f22;
        dy[3]  = -f2 - f16 - f17 - f23 + f15;
        dy[4]  = -f3 + 2.0f * f4 + f6 + f7 + f13 + f20;
        dy[5]  = -f6 - f8 - f14 - f20 + f3 + 2.0f * f18;
        dy[6]  = -f4 - f5 - f6 + f13;
        dy[7]  =  f4 + f5 + f6 + f7;
        dy[8]  = -f7 - f8;
        dy[9]  = -f12 + f7 + f9;
        dy[10] = -f9 - f10 + f8 + f11;
        dy[11] =  f9;
        dy[12] = -f11 + f10;
        dy[13] = -f13 + f12;
        dy[14] =  f14;
        dy[15] = -f18 - f19 + f16;
        dy[16] = -f20;
        dy[17] =  f20;
        dy[18] = -f21 - f22 - f24 + f23 + f25;
        dy[19] = -f25 + f24;

#pragma unroll
        for (int s = 0; s < 20; ++s) lds[t * PAD + s] = dy[s];
    }
    __syncthreads();

    // Dense store phase: block covers 256*20 floats = 1280 float4s.
    // Each output float4 J holds floats of exactly one column (20 % 4 == 0):
    // column q = J/5, starting species r = 4*(J%5) -> contiguous in LDS.
    float4* outv = (float4*)out;
    const int blockBaseF4 = blockIdx.x * 1280;
    const int nF4 = nvalid * 5;
#pragma unroll
    for (int i = 0; i < 5; ++i) {
        const int J = i * 256 + t;
        if (J < nF4) {
            const int q = J / 5;
            const int r = 4 * (J % 5);
            const float* p = &lds[q * PAD + r];
            outv[blockBaseF4 + J] = make_float4(p[0], p[1], p[2], p[3]);
        }
    }
}

extern "C" void kernel_launch(void* const* d_in, const int* in_sizes, int n_in,
                              void* d_out, int out_size, void* d_ws, size_t ws_size,
                              hipStream_t stream) {
    // d_in[0] = t (unused), d_in[1] = conc_in [20, B], d_in[2] = k [25]
    const float* conc = (const float*)d_in[1];
    const float* k    = (const float*)d_in[2];
    float* out        = (float*)d_out;

    const int block = 256;
    const int grid  = (B_TOTAL + block - 1) / block;
    pollu_kernel<<<grid, block, 0, stream>>>(conc, k, out);
}